// Round 1
// baseline (1073.161 us; speedup 1.0000x reference)
//
#include <hip/hip_runtime.h>

#define NN   25000
#define EE   400000
#define FIN  256
#define CC   32
#define AA   9
#define WN   288   // CC*AA
#define BB   8
#define HH   64
#define SS   4
#define FOUT 256

__device__ __forceinline__ float silu_f(float v){ return v / (1.0f + __expf(-v)); }

// ---------------- h = (x @ W1) * (1/sqrt(16)) : [N, 32] ----------------
__global__ __launch_bounds__(256) void k_h(const float* __restrict__ x,
                                           const float* __restrict__ W1,
                                           float* __restrict__ h){
  int gid = blockIdx.x * 256 + threadIdx.x;   // N*CC threads exactly
  int n = gid >> 5, c = gid & 31;
  const float* xr = x + (size_t)n * FIN;
  float acc = 0.f;
  #pragma unroll 8
  for (int f = 0; f < FIN; ++f) acc = fmaf(xr[f], W1[f * CC + c], acc);
  h[gid] = acc * 0.25f;
}

// ---------------- CSR-ish counting sort of edges by dst ----------------
__global__ __launch_bounds__(256) void k_hist(const int* __restrict__ eidx,
                                              int* __restrict__ cnt){
  int e = blockIdx.x * 256 + threadIdx.x;
  if (e < EE) atomicAdd(&cnt[eidx[e]], 1);
}

// single-block exclusive scan of cnt[NN] -> cur[NN]
__global__ __launch_bounds__(1024) void k_scan(const int* __restrict__ cnt,
                                               int* __restrict__ cur){
  __shared__ int part[1024];
  const int t = threadIdx.x;
  const int base = t * 25;                 // 1024*25 = 25600 >= NN
  int s = 0;
  for (int i = 0; i < 25; ++i){
    int idx = base + i;
    s += (idx < NN) ? cnt[idx] : 0;
  }
  part[t] = s;
  __syncthreads();
  for (int off = 1; off < 1024; off <<= 1){
    int v = (t >= off) ? part[t - off] : 0;
    __syncthreads();
    part[t] += v;
    __syncthreads();
  }
  int run = part[t] - s;                   // exclusive base for this thread
  for (int i = 0; i < 25; ++i){
    int idx = base + i;
    if (idx < NN){
      cur[idx] = run;
      run += cnt[idx];
    }
  }
}

__global__ __launch_bounds__(256) void k_scatter(const int* __restrict__ eidx,
                                                 int* __restrict__ cur,
                                                 int* __restrict__ perm){
  int e = blockIdx.x * 256 + threadIdx.x;
  if (e < EE){
    int d = eidx[e];
    int p = atomicAdd(&cur[d], 1);
    perm[p] = e;
  }
}

// ---------------- sc_out = (x ⊗ node_attrs) @ Wsc : [N, 256] ----------------
__global__ __launch_bounds__(256) void k_sc(const float* __restrict__ x,
                                            const float* __restrict__ na,
                                            const float* __restrict__ Wsc,
                                            float* __restrict__ out){
  __shared__ float As[32][64];
  __shared__ float Bs[32][64];
  const int row0 = blockIdx.x * 64;
  const int col0 = blockIdx.y * 64;
  const int tid = threadIdx.x;
  const int tm = tid >> 4, tn = tid & 15;
  float acc[4][4] = {};
  for (int kc = 0; kc < FIN * SS; kc += 32){
    #pragma unroll
    for (int t = 0; t < 8; ++t){
      int idx = tid + t * 256;
      int m = idx & 63, kk = idx >> 6;
      int n = row0 + m;
      int k = kc + kk;
      float v = 0.f;
      if (n < NN) v = x[(size_t)n * FIN + (k >> 2)] * na[n * SS + (k & 3)];
      As[kk][m] = v;
    }
    #pragma unroll
    for (int t = 0; t < 8; ++t){
      int idx = tid + t * 256;
      int o = idx & 63, kk = idx >> 6;
      Bs[kk][o] = Wsc[(size_t)(kc + kk) * FOUT + col0 + o];
    }
    __syncthreads();
    #pragma unroll
    for (int kk = 0; kk < 32; ++kk){
      float4 av = *(const float4*)&As[kk][tm * 4];
      float4 bv = *(const float4*)&Bs[kk][tn * 4];
      float a[4] = {av.x, av.y, av.z, av.w};
      float b[4] = {bv.x, bv.y, bv.z, bv.w};
      #pragma unroll
      for (int i = 0; i < 4; ++i)
        #pragma unroll
        for (int j = 0; j < 4; ++j)
          acc[i][j] = fmaf(a[i], b[j], acc[i][j]);
    }
    __syncthreads();
  }
  #pragma unroll
  for (int i = 0; i < 4; ++i){
    int n = row0 + tm * 4 + i;
    if (n < NN){
      float4 v = {acc[i][0], acc[i][1], acc[i][2], acc[i][3]};
      *(float4*)&out[(size_t)n * FOUT + col0 + tn * 4] = v;
    }
  }
}

// ---------------- fused edge MLP + tensor product + run-merged atomic scatter ----------------
// One block = 32 dst-sorted edges (via perm). t1=silu(ee@Wm1), t2=silu(t1@Wm2),
// w=t2@Wm3, msg = w * h[src,c] * sh[e,a]; consecutive same-dst edges merged
// in-register before atomicAdd into agg[dst].
__global__ __launch_bounds__(256) void k_edge(const float* __restrict__ eemb,
                                              const float* __restrict__ sh,
                                              const int* __restrict__ eidx,
                                              const int* __restrict__ perm,
                                              const float* __restrict__ h,
                                              const float* __restrict__ Wm1,
                                              const float* __restrict__ Wm2,
                                              const float* __restrict__ Wm3,
                                              float* __restrict__ agg){
  __shared__ float ee_s[32][8];
  __shared__ float sh_s[32][9];
  __shared__ float hs_s[32][32];
  __shared__ int   dst_s[32];
  __shared__ int   src_s[32];
  __shared__ int   pe_s[32];
  __shared__ float t1_s[64][36];   // [h][edge], padded stride 36
  __shared__ float t2_s[64][36];
  __shared__ float w3_s[8 * WN];   // 8-row chunk of Wm3 (was 16: LDS 43.5->34.3KB, 3->4 blocks/CU)
  const int tid = threadIdx.x;
  const int e0 = blockIdx.x * 32;

  if (tid < 32){
    int pe = perm[e0 + tid];
    pe_s[tid]  = pe;
    dst_s[tid] = eidx[pe];
    src_s[tid] = eidx[EE + pe];
  }
  __syncthreads();
  { int e = tid >> 3, b = tid & 7; ee_s[e][b] = eemb[(size_t)pe_s[e] * BB + b]; }
  for (int idx = tid; idx < 32 * AA; idx += 256){
    int e = idx / 9, a = idx - e * 9;
    sh_s[e][a] = sh[(size_t)pe_s[e] * AA + a];
  }
  #pragma unroll
  for (int r = 0; r < 4; ++r){
    int idx = tid + r * 256;
    int e = idx >> 5, c = idx & 31;
    hs_s[e][c] = h[(size_t)src_s[e] * CC + c];
  }
  __syncthreads();

  // layer 1: [32,8]@[8,64] -> t1
  {
    const int j = tid & 63, eg = tid >> 6;
    float acc[8] = {};
    #pragma unroll
    for (int b = 0; b < 8; ++b){
      float wv = Wm1[b * HH + j];
      #pragma unroll
      for (int e8 = 0; e8 < 8; ++e8) acc[e8] = fmaf(ee_s[eg * 8 + e8][b], wv, acc[e8]);
    }
    #pragma unroll
    for (int e8 = 0; e8 < 8; ++e8) t1_s[j][eg * 8 + e8] = silu_f(acc[e8]);
  }
  __syncthreads();

  // layer 2: [32,64]@[64,64] -> t2
  {
    const int j = tid & 63, eg = tid >> 6;
    float acc[8] = {};
    for (int hh = 0; hh < 64; ++hh){
      float wv = Wm2[hh * HH + j];
      float a[8];
      *(float4*)&a[0] = *(const float4*)&t1_s[hh][eg * 8];
      *(float4*)&a[4] = *(const float4*)&t1_s[hh][eg * 8 + 4];
      #pragma unroll
      for (int e8 = 0; e8 < 8; ++e8) acc[e8] = fmaf(a[e8], wv, acc[e8]);
    }
    #pragma unroll
    for (int e8 = 0; e8 < 8; ++e8) t2_s[j][eg * 8 + e8] = silu_f(acc[e8]);
  }

  // layer 3 + TP + scatter: thread = (te 0..7 -> 4 edges, tj 0..31 -> cols tj+32m)
  {
    const int tj = tid & 31, te = tid >> 5;
    float acc[4][9] = {};
    for (int hc = 0; hc < 8; ++hc){
      __syncthreads();   // also covers t2 store at hc=0
      #pragma unroll
      for (int t = 0; t < 9; ++t){
        int idx = tid + t * 256;
        w3_s[idx] = Wm3[(size_t)(hc * 8) * WN + idx];
      }
      __syncthreads();
      #pragma unroll
      for (int hh = 0; hh < 8; ++hh){
        float4 av = *(const float4*)&t2_s[hc * 8 + hh][te * 4];
        float a[4] = {av.x, av.y, av.z, av.w};
        #pragma unroll
        for (int m = 0; m < 9; ++m){
          float wv = w3_s[hh * WN + tj + 32 * m];
          #pragma unroll
          for (int i = 0; i < 4; ++i) acc[i][m] = fmaf(a[i], wv, acc[i][m]);
        }
      }
    }
    // finish TP (w * h * sh), then run-merge consecutive same-dst edges
    #pragma unroll
    for (int i = 0; i < 4; ++i){
      int e = te * 4 + i;
      #pragma unroll
      for (int m = 0; m < 9; ++m){
        int j = tj + 32 * m;
        int c = j / 9, a_ = j - c * 9;
        acc[i][m] *= hs_s[e][c] * sh_s[e][a_];
      }
    }
    #pragma unroll
    for (int i = 0; i < 4; ++i){
      int e = te * 4 + i;
      int d = dst_s[e];
      bool last = (i == 3) || (dst_s[e + 1] != d);
      if (!last){
        #pragma unroll
        for (int m = 0; m < 9; ++m) acc[i + 1][m] += acc[i][m];
      } else {
        #pragma unroll
        for (int m = 0; m < 9; ++m)
          atomicAdd(&agg[(size_t)d * WN + tj + 32 * m], acc[i][m]);
      }
    }
  }
}

// ---------------- out = silu(agg @ W2) + sc_out ----------------
__global__ __launch_bounds__(256) void k_out(const float* __restrict__ agg,
                                             const float* __restrict__ W2,
                                             float* __restrict__ out){
  __shared__ float As[32][64];
  __shared__ float Bs[32][64];
  const int row0 = blockIdx.x * 64;
  const int col0 = blockIdx.y * 64;
  const int tid = threadIdx.x;
  const int tm = tid >> 4, tn = tid & 15;
  float acc[4][4] = {};
  for (int kc = 0; kc < WN; kc += 32){
    #pragma unroll
    for (int t = 0; t < 8; ++t){
      int idx = tid + t * 256;
      int m = idx & 63, kk = idx >> 6;
      int n = row0 + m;
      float v = 0.f;
      if (n < NN) v = agg[(size_t)n * WN + kc + kk];
      As[kk][m] = v;
    }
    #pragma unroll
    for (int t = 0; t < 8; ++t){
      int idx = tid + t * 256;
      int o = idx & 63, kk = idx >> 6;
      Bs[kk][o] = W2[(size_t)(kc + kk) * FOUT + col0 + o];
    }
    __syncthreads();
    #pragma unroll
    for (int kk = 0; kk < 32; ++kk){
      float4 av = *(const float4*)&As[kk][tm * 4];
      float4 bv = *(const float4*)&Bs[kk][tn * 4];
      float a[4] = {av.x, av.y, av.z, av.w};
      float b[4] = {bv.x, bv.y, bv.z, bv.w};
      #pragma unroll
      for (int i = 0; i < 4; ++i)
        #pragma unroll
        for (int j = 0; j < 4; ++j)
          acc[i][j] = fmaf(a[i], b[j], acc[i][j]);
    }
    __syncthreads();
  }
  #pragma unroll
  for (int i = 0; i < 4; ++i){
    int n = row0 + tm * 4 + i;
    if (n < NN){
      float4 sc = *(const float4*)&out[(size_t)n * FOUT + col0 + tn * 4];
      float4 v;
      v.x = silu_f(acc[i][0]) + sc.x;
      v.y = silu_f(acc[i][1]) + sc.y;
      v.z = silu_f(acc[i][2]) + sc.z;
      v.w = silu_f(acc[i][3]) + sc.w;
      *(float4*)&out[(size_t)n * FOUT + col0 + tn * 4] = v;
    }
  }
}

extern "C" void kernel_launch(void* const* d_in, const int* in_sizes, int n_in,
                              void* d_out, int out_size, void* d_ws, size_t ws_size,
                              hipStream_t stream){
  const float* x    = (const float*)d_in[0];
  const float* na   = (const float*)d_in[1];
  const float* eemb = (const float*)d_in[2];
  const float* shp  = (const float*)d_in[3];
  const int*   eidx = (const int*)d_in[4];
  const float* W1   = (const float*)d_in[5];
  const float* Wm1  = (const float*)d_in[6];
  const float* Wm2  = (const float*)d_in[7];
  const float* Wm3  = (const float*)d_in[8];
  const float* W2   = (const float*)d_in[9];
  const float* Wsc  = (const float*)d_in[10];
  float* out  = (float*)d_out;
  float* agg  = (float*)d_ws;                    // [N, 288]
  float* hbuf = agg + (size_t)NN * WN;           // [N, 32]
  int*   cnt  = (int*)(hbuf + (size_t)NN * CC);  // [N]
  int*   cur  = cnt + NN;                        // [N]
  int*   perm = cur + NN;                        // [E]

  hipMemsetAsync(agg, 0, (size_t)NN * WN * sizeof(float), stream);
  hipMemsetAsync(cnt, 0, (size_t)NN * sizeof(int), stream);
  k_hist   <<<dim3((EE + 255) / 256), dim3(256),  0, stream>>>(eidx, cnt);
  k_scan   <<<dim3(1),                dim3(1024), 0, stream>>>(cnt, cur);
  k_scatter<<<dim3((EE + 255) / 256), dim3(256),  0, stream>>>(eidx, cur, perm);
  k_h  <<<dim3(NN * CC / 256), dim3(256), 0, stream>>>(x, W1, hbuf);
  k_sc <<<dim3((NN + 63) / 64, FOUT / 64), dim3(256), 0, stream>>>(x, na, Wsc, out);
  k_edge<<<dim3(EE / 32), dim3(256), 0, stream>>>(eemb, shp, eidx, perm, hbuf, Wm1, Wm2, Wm3, agg);
  k_out<<<dim3((NN + 63) / 64, FOUT / 64), dim3(256), 0, stream>>>(agg, W2, out);
}

// Round 2
// 926.813 us; speedup vs baseline: 1.1579x; 1.1579x over previous
//
#include <hip/hip_runtime.h>

#define NN   25000
#define EE   400000
#define FIN  256
#define CC   32
#define AA   9
#define WN   288   // CC*AA
#define BB   8
#define HH   64
#define SS   4
#define FOUT 256
#define EPB  64    // edges per block in k_edge

typedef float f32x4 __attribute__((ext_vector_type(4)));
typedef short short8 __attribute__((ext_vector_type(8)));

__device__ __forceinline__ float silu_f(float v){ return v / (1.0f + __expf(-v)); }

// round-to-nearest-even float -> bf16 bits
__device__ __forceinline__ unsigned short f2bf(float f){
  unsigned int u = __builtin_bit_cast(unsigned int, f);
  u += 0x7FFFu + ((u >> 16) & 1u);
  return (unsigned short)(u >> 16);
}

// ---------------- h = (x @ W1) * (1/sqrt(16)) : [N, 32] ----------------
__global__ __launch_bounds__(256) void k_h(const float* __restrict__ x,
                                           const float* __restrict__ W1,
                                           float* __restrict__ h){
  int gid = blockIdx.x * 256 + threadIdx.x;   // N*CC threads exactly
  int n = gid >> 5, c = gid & 31;
  const float* xr = x + (size_t)n * FIN;
  float acc = 0.f;
  #pragma unroll 8
  for (int f = 0; f < FIN; ++f) acc = fmaf(xr[f], W1[f * CC + c], acc);
  h[gid] = acc * 0.25f;
}

// ---------------- one-shot: Wm2 -> Wm2^T bf16, Wm3 -> Wm3^T bf16 ----------------
__global__ __launch_bounds__(256) void k_cvt(const float* __restrict__ Wm2,
                                             const float* __restrict__ Wm3,
                                             unsigned short* __restrict__ wm2t,
                                             unsigned short* __restrict__ wm3t){
  int i = blockIdx.x * 256 + threadIdx.x;
  if (i < HH * HH){           // wm2t[n][k] = Wm2[k][n]
    int n = i >> 6, k = i & 63;
    wm2t[n * 64 + k] = f2bf(Wm2[k * HH + n]);
  }
  if (i < WN * HH){           // wm3t[n][k] = Wm3[k][n]
    int n = i >> 6, k = i & 63;
    wm3t[n * 64 + k] = f2bf(Wm3[k * WN + n]);
  }
}

// ---------------- CSR-ish counting sort of edges by dst ----------------
__global__ __launch_bounds__(256) void k_hist(const int* __restrict__ eidx,
                                              int* __restrict__ cnt){
  int e = blockIdx.x * 256 + threadIdx.x;
  if (e < EE) atomicAdd(&cnt[eidx[e]], 1);
}

__global__ __launch_bounds__(1024) void k_scan(const int* __restrict__ cnt,
                                               int* __restrict__ cur){
  __shared__ int part[1024];
  const int t = threadIdx.x;
  const int base = t * 25;                 // 1024*25 = 25600 >= NN
  int s = 0;
  for (int i = 0; i < 25; ++i){
    int idx = base + i;
    s += (idx < NN) ? cnt[idx] : 0;
  }
  part[t] = s;
  __syncthreads();
  for (int off = 1; off < 1024; off <<= 1){
    int v = (t >= off) ? part[t - off] : 0;
    __syncthreads();
    part[t] += v;
    __syncthreads();
  }
  int run = part[t] - s;                   // exclusive base for this thread
  for (int i = 0; i < 25; ++i){
    int idx = base + i;
    if (idx < NN){
      cur[idx] = run;
      run += cnt[idx];
    }
  }
}

__global__ __launch_bounds__(256) void k_scatter(const int* __restrict__ eidx,
                                                 int* __restrict__ cur,
                                                 int* __restrict__ perm){
  int e = blockIdx.x * 256 + threadIdx.x;
  if (e < EE){
    int d = eidx[e];
    int p = atomicAdd(&cur[d], 1);
    perm[p] = e;
  }
}

// ---------------- sc_out = (x ⊗ node_attrs) @ Wsc : [N, 256] ----------------
__global__ __launch_bounds__(256) void k_sc(const float* __restrict__ x,
                                            const float* __restrict__ na,
                                            const float* __restrict__ Wsc,
                                            float* __restrict__ out){
  __shared__ float As[32][64];
  __shared__ float Bs[32][64];
  const int row0 = blockIdx.x * 64;
  const int col0 = blockIdx.y * 64;
  const int tid = threadIdx.x;
  const int tm = tid >> 4, tn = tid & 15;
  float acc[4][4] = {};
  for (int kc = 0; kc < FIN * SS; kc += 32){
    #pragma unroll
    for (int t = 0; t < 8; ++t){
      int idx = tid + t * 256;
      int m = idx & 63, kk = idx >> 6;
      int n = row0 + m;
      int k = kc + kk;
      float v = 0.f;
      if (n < NN) v = x[(size_t)n * FIN + (k >> 2)] * na[n * SS + (k & 3)];
      As[kk][m] = v;
    }
    #pragma unroll
    for (int t = 0; t < 8; ++t){
      int idx = tid + t * 256;
      int o = idx & 63, kk = idx >> 6;
      Bs[kk][o] = Wsc[(size_t)(kc + kk) * FOUT + col0 + o];
    }
    __syncthreads();
    #pragma unroll
    for (int kk = 0; kk < 32; ++kk){
      float4 av = *(const float4*)&As[kk][tm * 4];
      float4 bv = *(const float4*)&Bs[kk][tn * 4];
      float a[4] = {av.x, av.y, av.z, av.w};
      float b[4] = {bv.x, bv.y, bv.z, bv.w};
      #pragma unroll
      for (int i = 0; i < 4; ++i)
        #pragma unroll
        for (int j = 0; j < 4; ++j)
          acc[i][j] = fmaf(a[i], b[j], acc[i][j]);
    }
    __syncthreads();
  }
  #pragma unroll
  for (int i = 0; i < 4; ++i){
    int n = row0 + tm * 4 + i;
    if (n < NN){
      float4 v = {acc[i][0], acc[i][1], acc[i][2], acc[i][3]};
      *(float4*)&out[(size_t)n * FOUT + col0 + tn * 4] = v;
    }
  }
}

// ---------------- fused edge MLP (bf16 MFMA) + TP + run-merged atomic scatter ----------------
// 64 dst-sorted edges per block, 4 waves; wave w owns edges [w*16, w*16+16).
// layer1 fp32 VALU -> t1b bf16 (LDS); layer2/3 via mfma_f32_16x16x32_bf16 with
// B = Wm2^T/Wm3^T bf16 read straight from global (L1/L2-resident, shared by all blocks).
// All inter-layer dataflow is intra-wave => only 2 block barriers (both for the gathers).
__global__ __launch_bounds__(256) void k_edge(const float* __restrict__ eemb,
                                              const float* __restrict__ sh,
                                              const int* __restrict__ eidx,
                                              const int* __restrict__ perm,
                                              const float* __restrict__ h,
                                              const float* __restrict__ Wm1,
                                              const unsigned short* __restrict__ wm2t,
                                              const unsigned short* __restrict__ wm3t,
                                              float* __restrict__ agg){
  __shared__ float ee_s[EPB][8];                    // 2 KB
  __shared__ float sh_s[EPB][12];                   // 3 KB (stride 12 vs 9: bank spread)
  __shared__ float hs_s[EPB][32];                   // 8 KB
  __shared__ int   dst_s[EPB];
  __shared__ int   src_s[EPB];
  __shared__ int   pe_s[EPB];
  __shared__ __align__(16) unsigned short t1b[EPB][72];  // 9 KB, stride 144B (2-way max)
  __shared__ __align__(16) unsigned short t2b[EPB][72];  // 9 KB
  const int tid = threadIdx.x;
  const int e0 = blockIdx.x * EPB;

  if (tid < EPB){
    int pe = perm[e0 + tid];
    pe_s[tid]  = pe;
    dst_s[tid] = eidx[pe];
    src_s[tid] = eidx[EE + pe];
  }
  __syncthreads();
  { int i = tid;        int e = i >> 3, b = i & 7; ee_s[e][b] = eemb[(size_t)pe_s[e] * BB + b]; }
  { int i = tid + 256;  int e = i >> 3, b = i & 7; ee_s[e][b] = eemb[(size_t)pe_s[e] * BB + b]; }
  for (int i = tid; i < EPB * AA; i += 256){
    int e = i / 9, a = i - e * 9;
    sh_s[e][a] = sh[(size_t)pe_s[e] * AA + a];
  }
  #pragma unroll
  for (int r = 0; r < 8; ++r){
    int i = tid + r * 256;
    int e = i >> 5, c = i & 31;
    hs_s[e][c] = h[(size_t)src_s[e] * CC + c];
  }
  __syncthreads();

  // ---- layer 1 (fp32): t1[e][j] = silu(ee[e] . Wm1[:,j]), stored bf16 ----
  // thread: j2 = pair of h columns, eg = 8-edge group; wave w covers exactly edges [16w,16w+16)
  {
    const int j2 = tid & 31;
    const int eg = tid >> 5;
    float w0[8], w1[8];
    #pragma unroll
    for (int b = 0; b < 8; ++b){
      w0[b] = Wm1[b * HH + 2 * j2];
      w1[b] = Wm1[b * HH + 2 * j2 + 1];
    }
    #pragma unroll
    for (int e8 = 0; e8 < 8; ++e8){
      int e = eg * 8 + e8;
      float a0 = 0.f, a1 = 0.f;
      #pragma unroll
      for (int b = 0; b < 8; ++b){
        float ev = ee_s[e][b];
        a0 = fmaf(ev, w0[b], a0);
        a1 = fmaf(ev, w1[b], a1);
      }
      a0 = silu_f(a0); a1 = silu_f(a1);
      unsigned int pk = (unsigned int)f2bf(a0) | ((unsigned int)f2bf(a1) << 16);
      *(unsigned int*)&t1b[e][j2 * 2] = pk;
    }
  }
  // no barrier: t1b rows [16w,16w+16) written and read by wave w only

  const int lane = tid & 63;
  const int wv   = tid >> 6;
  const int row  = lane & 15;       // M/N index within 16x16 tile
  const int kg   = lane >> 4;       // k-group (8 bf16 each, +32 for kstep 1)
  const f32x4 zf = {0.f, 0.f, 0.f, 0.f};

  // ---- layer 2 (MFMA): t2[64e][64h] = silu(t1 @ Wm2) ----
  {
    short8 a2k0 = *(const short8*)&t1b[wv * 16 + row][kg * 8];
    short8 a2k1 = *(const short8*)&t1b[wv * 16 + row][kg * 8 + 32];
    #pragma unroll
    for (int nt = 0; nt < 4; ++nt){
      const unsigned short* bp = wm2t + (size_t)((nt * 16 + row) * 64 + kg * 8);
      short8 b0 = *(const short8*)bp;
      short8 b1 = *(const short8*)(bp + 32);
      f32x4 acc = __builtin_amdgcn_mfma_f32_16x16x32_bf16(a2k0, b0, zf, 0, 0, 0);
      acc = __builtin_amdgcn_mfma_f32_16x16x32_bf16(a2k1, b1, acc, 0, 0, 0);
      // D: col = lane&15 -> h = nt*16+row ; rows = kg*4+r -> edge
      #pragma unroll
      for (int r = 0; r < 4; ++r){
        int e = wv * 16 + kg * 4 + r;
        t2b[e][nt * 16 + row] = f2bf(silu_f(acc[r]));
      }
    }
  }
  // no barrier: t2b rows [16w,16w+16) written and read by wave w only

  // ---- layer 3 (MFMA) + TP + scatter ----
  {
    short8 a3k0 = *(const short8*)&t2b[wv * 16 + row][kg * 8];
    short8 a3k1 = *(const short8*)&t2b[wv * 16 + row][kg * 8 + 32];
    const int ebase = wv * 16 + kg * 4;
    for (int nt = 0; nt < 18; ++nt){
      const unsigned short* bp = wm3t + (size_t)((nt * 16 + row) * 64 + kg * 8);
      short8 b0 = *(const short8*)bp;
      short8 b1 = *(const short8*)(bp + 32);
      f32x4 acc = __builtin_amdgcn_mfma_f32_16x16x32_bf16(a3k0, b0, zf, 0, 0, 0);
      acc = __builtin_amdgcn_mfma_f32_16x16x32_bf16(a3k1, b1, acc, 0, 0, 0);
      int j = nt * 16 + row;             // output col in [0,288)
      int c = j / 9, a_ = j - c * 9;
      float vals[4];
      #pragma unroll
      for (int r = 0; r < 4; ++r){
        int e = ebase + r;
        vals[r] = acc[r] * hs_s[e][c] * sh_s[e][a_];
      }
      #pragma unroll
      for (int r = 0; r < 4; ++r){
        int e = ebase + r;
        int d = dst_s[e];
        bool last = (r == 3) || (dst_s[e + 1] != d);
        if (!last){
          vals[r + 1] += vals[r];
        } else {
          atomicAdd(&agg[(size_t)d * WN + j], vals[r]);
        }
      }
    }
  }
}

// ---------------- out = silu(agg @ W2) + sc_out ----------------
__global__ __launch_bounds__(256) void k_out(const float* __restrict__ agg,
                                             const float* __restrict__ W2,
                                             float* __restrict__ out){
  __shared__ float As[32][64];
  __shared__ float Bs[32][64];
  const int row0 = blockIdx.x * 64;
  const int col0 = blockIdx.y * 64;
  const int tid = threadIdx.x;
  const int tm = tid >> 4, tn = tid & 15;
  float acc[4][4] = {};
  for (int kc = 0; kc < WN; kc += 32){
    #pragma unroll
    for (int t = 0; t < 8; ++t){
      int idx = tid + t * 256;
      int m = idx & 63, kk = idx >> 6;
      int n = row0 + m;
      float v = 0.f;
      if (n < NN) v = agg[(size_t)n * WN + kc + kk];
      As[kk][m] = v;
    }
    #pragma unroll
    for (int t = 0; t < 8; ++t){
      int idx = tid + t * 256;
      int o = idx & 63, kk = idx >> 6;
      Bs[kk][o] = W2[(size_t)(kc + kk) * FOUT + col0 + o];
    }
    __syncthreads();
    #pragma unroll
    for (int kk = 0; kk < 32; ++kk){
      float4 av = *(const float4*)&As[kk][tm * 4];
      float4 bv = *(const float4*)&Bs[kk][tn * 4];
      float a[4] = {av.x, av.y, av.z, av.w};
      float b[4] = {bv.x, bv.y, bv.z, bv.w};
      #pragma unroll
      for (int i = 0; i < 4; ++i)
        #pragma unroll
        for (int j = 0; j < 4; ++j)
          acc[i][j] = fmaf(a[i], b[j], acc[i][j]);
    }
    __syncthreads();
  }
  #pragma unroll
  for (int i = 0; i < 4; ++i){
    int n = row0 + tm * 4 + i;
    if (n < NN){
      float4 sc = *(const float4*)&out[(size_t)n * FOUT + col0 + tn * 4];
      float4 v;
      v.x = silu_f(acc[i][0]) + sc.x;
      v.y = silu_f(acc[i][1]) + sc.y;
      v.z = silu_f(acc[i][2]) + sc.z;
      v.w = silu_f(acc[i][3]) + sc.w;
      *(float4*)&out[(size_t)n * FOUT + col0 + tn * 4] = v;
    }
  }
}

extern "C" void kernel_launch(void* const* d_in, const int* in_sizes, int n_in,
                              void* d_out, int out_size, void* d_ws, size_t ws_size,
                              hipStream_t stream){
  const float* x    = (const float*)d_in[0];
  const float* na   = (const float*)d_in[1];
  const float* eemb = (const float*)d_in[2];
  const float* shp  = (const float*)d_in[3];
  const int*   eidx = (const int*)d_in[4];
  const float* W1   = (const float*)d_in[5];
  const float* Wm1  = (const float*)d_in[6];
  const float* Wm2  = (const float*)d_in[7];
  const float* Wm3  = (const float*)d_in[8];
  const float* W2   = (const float*)d_in[9];
  const float* Wsc  = (const float*)d_in[10];
  float* out  = (float*)d_out;
  float* agg  = (float*)d_ws;                       // [N, 288] f32
  float* hbuf = agg + (size_t)NN * WN;              // [N, 32] f32
  int*   cnt  = (int*)(hbuf + (size_t)NN * CC);     // [N]
  int*   cur  = cnt + NN;                           // [N]
  int*   perm = cur + NN;                           // [E]
  unsigned short* wm2t = (unsigned short*)(perm + EE);   // [64*64] bf16
  unsigned short* wm3t = wm2t + HH * HH;                 // [288*64] bf16

  hipMemsetAsync(agg, 0, (size_t)NN * WN * sizeof(float), stream);
  hipMemsetAsync(cnt, 0, (size_t)NN * sizeof(int), stream);
  k_cvt    <<<dim3((WN * HH + 255) / 256), dim3(256), 0, stream>>>(Wm2, Wm3, wm2t, wm3t);
  k_hist   <<<dim3((EE + 255) / 256), dim3(256),  0, stream>>>(eidx, cnt);
  k_scan   <<<dim3(1),                dim3(1024), 0, stream>>>(cnt, cur);
  k_scatter<<<dim3((EE + 255) / 256), dim3(256),  0, stream>>>(eidx, cur, perm);
  k_h  <<<dim3(NN * CC / 256), dim3(256), 0, stream>>>(x, W1, hbuf);
  k_sc <<<dim3((NN + 63) / 64, FOUT / 64), dim3(256), 0, stream>>>(x, na, Wsc, out);
  k_edge<<<dim3(EE / EPB), dim3(256), 0, stream>>>(eemb, shp, eidx, perm, hbuf, Wm1, wm2t, wm3t, agg);
  k_out<<<dim3((NN + 63) / 64, FOUT / 64), dim3(256), 0, stream>>>(agg, W2, out);
}

// Round 3
// 646.956 us; speedup vs baseline: 1.6588x; 1.4326x over previous
//
#include <hip/hip_runtime.h>

#define NN   25000
#define EE   400000
#define FIN  256
#define CC   32
#define AA   9
#define WN   288   // CC*AA
#define BB   8
#define HH   64
#define SS   4
#define FOUT 256
#define EPB  64    // edges per block in k_edge

typedef float f32x4 __attribute__((ext_vector_type(4)));
typedef short short8 __attribute__((ext_vector_type(8)));

__device__ __forceinline__ float silu_f(float v){ return v / (1.0f + __expf(-v)); }

// round-to-nearest-even float -> bf16 bits
__device__ __forceinline__ unsigned short f2bf(float f){
  unsigned int u = __builtin_bit_cast(unsigned int, f);
  u += 0x7FFFu + ((u >> 16) & 1u);
  return (unsigned short)(u >> 16);
}

// ---------------- h = (x @ W1) * (1/sqrt(16)) : [N, 32] ----------------
__global__ __launch_bounds__(256) void k_h(const float* __restrict__ x,
                                           const float* __restrict__ W1,
                                           float* __restrict__ h){
  int gid = blockIdx.x * 256 + threadIdx.x;   // N*CC threads exactly
  int n = gid >> 5, c = gid & 31;
  const float* xr = x + (size_t)n * FIN;
  float acc = 0.f;
  #pragma unroll 8
  for (int f = 0; f < FIN; ++f) acc = fmaf(xr[f], W1[f * CC + c], acc);
  h[gid] = acc * 0.25f;
}

// ---------------- one-shot: Wm2 -> Wm2^T bf16, Wm3 -> Wm3^T bf16 ----------------
__global__ __launch_bounds__(256) void k_cvt(const float* __restrict__ Wm2,
                                             const float* __restrict__ Wm3,
                                             unsigned short* __restrict__ wm2t,
                                             unsigned short* __restrict__ wm3t){
  int i = blockIdx.x * 256 + threadIdx.x;
  if (i < HH * HH){           // wm2t[n][k] = Wm2[k][n]
    int n = i >> 6, k = i & 63;
    wm2t[n * 64 + k] = f2bf(Wm2[k * HH + n]);
  }
  if (i < WN * HH){           // wm3t[n][k] = Wm3[k][n]
    int n = i >> 6, k = i & 63;
    wm3t[n * 64 + k] = f2bf(Wm3[k * WN + n]);
  }
}

// ---------------- one-shot: Wsc [1024 k][256 n] f32 -> wscb [256 n][1024 k] bf16 ----------------
__global__ __launch_bounds__(256) void k_cvtsc(const float* __restrict__ Wsc,
                                               unsigned short* __restrict__ wscb){
  __shared__ float tile[32][33];
  const int k0 = blockIdx.x * 32;
  const int n0 = blockIdx.y * 32;
  const int t = threadIdx.x;
  #pragma unroll
  for (int p = 0; p < 4; ++p){
    int idx = t + p * 256;
    int r = idx >> 5, c = idx & 31;       // r: k-offset, c: n-offset
    tile[r][c] = Wsc[(size_t)(k0 + r) * 256 + n0 + c];
  }
  __syncthreads();
  #pragma unroll
  for (int p = 0; p < 4; ++p){
    int idx = t + p * 256;
    int r = idx >> 5, c = idx & 31;       // r: n-offset, c: k-offset
    wscb[(size_t)(n0 + r) * 1024 + k0 + c] = f2bf(tile[c][r]);
  }
}

// ---------------- CSR-ish counting sort of edges by dst ----------------
__global__ __launch_bounds__(256) void k_hist(const int* __restrict__ eidx,
                                              int* __restrict__ cnt){
  int e = blockIdx.x * 256 + threadIdx.x;
  if (e < EE) atomicAdd(&cnt[eidx[e]], 1);
}

__global__ __launch_bounds__(1024) void k_scan(const int* __restrict__ cnt,
                                               int* __restrict__ cur){
  __shared__ int part[1024];
  const int t = threadIdx.x;
  const int base = t * 25;                 // 1024*25 = 25600 >= NN
  int s = 0;
  for (int i = 0; i < 25; ++i){
    int idx = base + i;
    s += (idx < NN) ? cnt[idx] : 0;
  }
  part[t] = s;
  __syncthreads();
  for (int off = 1; off < 1024; off <<= 1){
    int v = (t >= off) ? part[t - off] : 0;
    __syncthreads();
    part[t] += v;
    __syncthreads();
  }
  int run = part[t] - s;                   // exclusive base for this thread
  for (int i = 0; i < 25; ++i){
    int idx = base + i;
    if (idx < NN){
      cur[idx] = run;
      run += cnt[idx];
    }
  }
}

__global__ __launch_bounds__(256) void k_scatter(const int* __restrict__ eidx,
                                                 int* __restrict__ cur,
                                                 int* __restrict__ perm){
  int e = blockIdx.x * 256 + threadIdx.x;
  if (e < EE){
    int d = eidx[e];
    int p = atomicAdd(&cur[d], 1);
    perm[p] = e;
  }
}

// ---------------- sc_out = (x ⊗ node_attrs) @ Wsc via bf16 MFMA ----------------
// C[25000,256] = A[25000,1024] @ B[1024,256], A[m,k] = x[m,k>>2]*na[m,k&3] built
// on the fly (bf16), B pre-transposed to wscb[n][k] bf16. BM=64 BN=256 BK=64,
// 4 waves x 16 rows. Same verified fragment pattern as k_edge.
__global__ __launch_bounds__(256) void k_sc(const float* __restrict__ x,
                                            const float* __restrict__ na,
                                            const unsigned short* __restrict__ wscb,
                                            float* __restrict__ out){
  __shared__ __align__(16) unsigned short As[64][72];    // 9 KB, stride 144 B
  __shared__ __align__(16) unsigned short Bs[256][72];   // 36 KB
  const int tid = threadIdx.x;
  const int m0 = blockIdx.x * 64;
  const int sm = tid >> 2;          // staging row 0..63
  const int sq = tid & 3;           // staging k-quarter
  float4 nav = {0.f, 0.f, 0.f, 0.f};
  if (m0 + sm < NN) nav = *(const float4*)&na[(size_t)(m0 + sm) * SS];
  const float nf[4] = {nav.x, nav.y, nav.z, nav.w};
  const int lane = tid & 63, wv = tid >> 6;
  const int row = lane & 15, kg = lane >> 4;
  const f32x4 zf = {0.f, 0.f, 0.f, 0.f};
  f32x4 acc[16];
  #pragma unroll
  for (int i = 0; i < 16; ++i) acc[i] = zf;

  for (int kc = 0; kc < FIN * SS; kc += 64){
    __syncthreads();
    // stage A: A[sm][sq*16 .. +16] ; f-range = kc/4 + sq*4 .. +4 (coalesced x float4)
    {
      float4 xv = {0.f, 0.f, 0.f, 0.f};
      int fc4 = (kc >> 2) + sq * 4;
      if (m0 + sm < NN) xv = *(const float4*)&x[(size_t)(m0 + sm) * FIN + fc4];
      float xf[4] = {xv.x, xv.y, xv.z, xv.w};
      unsigned short tmp[16];
      #pragma unroll
      for (int f = 0; f < 4; ++f)
        #pragma unroll
        for (int s = 0; s < 4; ++s) tmp[f * 4 + s] = f2bf(xf[f] * nf[s]);
      *(short8*)&As[sm][sq * 16]     = *(short8*)&tmp[0];
      *(short8*)&As[sm][sq * 16 + 8] = *(short8*)&tmp[8];
    }
    // stage B: 256 n-rows x 64 k bf16 (contiguous 128 B per n-row from wscb)
    #pragma unroll
    for (int r = 0; r < 4; ++r){
      int ch = tid + r * 256;         // 0..1023
      int n = ch >> 2, c4 = ch & 3;
      const unsigned short* src = wscb + (size_t)n * 1024 + kc + c4 * 16;
      *(short8*)&Bs[n][c4 * 16]     = *(const short8*)src;
      *(short8*)&Bs[n][c4 * 16 + 8] = *(const short8*)(src + 8);
    }
    __syncthreads();
    #pragma unroll
    for (int ks = 0; ks < 2; ++ks){
      short8 af = *(const short8*)&As[wv * 16 + row][ks * 32 + kg * 8];
      #pragma unroll
      for (int nt = 0; nt < 16; ++nt){
        short8 bfr = *(const short8*)&Bs[nt * 16 + row][ks * 32 + kg * 8];
        acc[nt] = __builtin_amdgcn_mfma_f32_16x16x32_bf16(af, bfr, acc[nt], 0, 0, 0);
      }
    }
  }
  // D: col(n within tile) = lane&15, row(m within wave) = kg*4 + r
  #pragma unroll
  for (int nt = 0; nt < 16; ++nt){
    #pragma unroll
    for (int r = 0; r < 4; ++r){
      int m = m0 + wv * 16 + kg * 4 + r;
      if (m < NN) out[(size_t)m * FOUT + nt * 16 + row] = acc[nt][r];
    }
  }
}

// ---------------- fused edge MLP (bf16 MFMA) + TP + run-merged atomic scatter ----------------
__global__ __launch_bounds__(256) void k_edge(const float* __restrict__ eemb,
                                              const float* __restrict__ sh,
                                              const int* __restrict__ eidx,
                                              const int* __restrict__ perm,
                                              const float* __restrict__ h,
                                              const float* __restrict__ Wm1,
                                              const unsigned short* __restrict__ wm2t,
                                              const unsigned short* __restrict__ wm3t,
                                              float* __restrict__ agg){
  __shared__ float ee_s[EPB][8];                    // 2 KB
  __shared__ float sh_s[EPB][12];                   // 3 KB
  __shared__ float hs_s[EPB][32];                   // 8 KB
  __shared__ int   dst_s[EPB];
  __shared__ int   src_s[EPB];
  __shared__ int   pe_s[EPB];
  __shared__ __align__(16) unsigned short t1b[EPB][72];  // 9 KB
  __shared__ __align__(16) unsigned short t2b[EPB][72];  // 9 KB
  const int tid = threadIdx.x;
  const int e0 = blockIdx.x * EPB;

  if (tid < EPB){
    int pe = perm[e0 + tid];
    pe_s[tid]  = pe;
    dst_s[tid] = eidx[pe];
    src_s[tid] = eidx[EE + pe];
  }
  __syncthreads();
  { int i = tid;        int e = i >> 3, b = i & 7; ee_s[e][b] = eemb[(size_t)pe_s[e] * BB + b]; }
  { int i = tid + 256;  int e = i >> 3, b = i & 7; ee_s[e][b] = eemb[(size_t)pe_s[e] * BB + b]; }
  for (int i = tid; i < EPB * AA; i += 256){
    int e = i / 9, a = i - e * 9;
    sh_s[e][a] = sh[(size_t)pe_s[e] * AA + a];
  }
  #pragma unroll
  for (int r = 0; r < 8; ++r){
    int i = tid + r * 256;
    int e = i >> 5, c = i & 31;
    hs_s[e][c] = h[(size_t)src_s[e] * CC + c];
  }
  __syncthreads();

  // ---- layer 1 (fp32): t1[e][j] = silu(ee[e] . Wm1[:,j]), stored bf16 ----
  {
    const int j2 = tid & 31;
    const int eg = tid >> 5;
    float w0[8], w1[8];
    #pragma unroll
    for (int b = 0; b < 8; ++b){
      w0[b] = Wm1[b * HH + 2 * j2];
      w1[b] = Wm1[b * HH + 2 * j2 + 1];
    }
    #pragma unroll
    for (int e8 = 0; e8 < 8; ++e8){
      int e = eg * 8 + e8;
      float a0 = 0.f, a1 = 0.f;
      #pragma unroll
      for (int b = 0; b < 8; ++b){
        float ev = ee_s[e][b];
        a0 = fmaf(ev, w0[b], a0);
        a1 = fmaf(ev, w1[b], a1);
      }
      a0 = silu_f(a0); a1 = silu_f(a1);
      unsigned int pk = (unsigned int)f2bf(a0) | ((unsigned int)f2bf(a1) << 16);
      *(unsigned int*)&t1b[e][j2 * 2] = pk;
    }
  }
  // no barrier: t1b rows [16w,16w+16) written and read by wave w only

  const int lane = tid & 63;
  const int wv   = tid >> 6;
  const int row  = lane & 15;
  const int kg   = lane >> 4;
  const f32x4 zf = {0.f, 0.f, 0.f, 0.f};

  // ---- layer 2 (MFMA): t2[64e][64h] = silu(t1 @ Wm2) ----
  {
    short8 a2k0 = *(const short8*)&t1b[wv * 16 + row][kg * 8];
    short8 a2k1 = *(const short8*)&t1b[wv * 16 + row][kg * 8 + 32];
    #pragma unroll
    for (int nt = 0; nt < 4; ++nt){
      const unsigned short* bp = wm2t + (size_t)((nt * 16 + row) * 64 + kg * 8);
      short8 b0 = *(const short8*)bp;
      short8 b1 = *(const short8*)(bp + 32);
      f32x4 acc = __builtin_amdgcn_mfma_f32_16x16x32_bf16(a2k0, b0, zf, 0, 0, 0);
      acc = __builtin_amdgcn_mfma_f32_16x16x32_bf16(a2k1, b1, acc, 0, 0, 0);
      #pragma unroll
      for (int r = 0; r < 4; ++r){
        int e = wv * 16 + kg * 4 + r;
        t2b[e][nt * 16 + row] = f2bf(silu_f(acc[r]));
      }
    }
  }
  // no barrier: t2b rows [16w,16w+16) written and read by wave w only

  // ---- layer 3 (MFMA) + TP + scatter ----
  {
    short8 a3k0 = *(const short8*)&t2b[wv * 16 + row][kg * 8];
    short8 a3k1 = *(const short8*)&t2b[wv * 16 + row][kg * 8 + 32];
    const int ebase = wv * 16 + kg * 4;
    for (int nt = 0; nt < 18; ++nt){
      const unsigned short* bp = wm3t + (size_t)((nt * 16 + row) * 64 + kg * 8);
      short8 b0 = *(const short8*)bp;
      short8 b1 = *(const short8*)(bp + 32);
      f32x4 acc = __builtin_amdgcn_mfma_f32_16x16x32_bf16(a3k0, b0, zf, 0, 0, 0);
      acc = __builtin_amdgcn_mfma_f32_16x16x32_bf16(a3k1, b1, acc, 0, 0, 0);
      int j = nt * 16 + row;             // output col in [0,288)
      int c = j / 9, a_ = j - c * 9;
      float vals[4];
      #pragma unroll
      for (int r = 0; r < 4; ++r){
        int e = ebase + r;
        vals[r] = acc[r] * hs_s[e][c] * sh_s[e][a_];
      }
      #pragma unroll
      for (int r = 0; r < 4; ++r){
        int e = ebase + r;
        int d = dst_s[e];
        bool last = (r == 3) || (dst_s[e + 1] != d);
        if (!last){
          vals[r + 1] += vals[r];
        } else {
          atomicAdd(&agg[(size_t)d * WN + j], vals[r]);
        }
      }
    }
  }
}

// ---------------- out = silu(agg @ W2) + sc_out ----------------
__global__ __launch_bounds__(256) void k_out(const float* __restrict__ agg,
                                             const float* __restrict__ W2,
                                             float* __restrict__ out){
  __shared__ float As[32][68];   // padded: float4-aligned rows, spread banks
  __shared__ float Bs[32][64];
  const int row0 = blockIdx.x * 64;
  const int col0 = blockIdx.y * 64;
  const int tid = threadIdx.x;
  const int tm = tid >> 4, tn = tid & 15;
  float acc[4][4] = {};
  for (int kc = 0; kc < WN; kc += 32){
    #pragma unroll
    for (int t = 0; t < 8; ++t){
      int idx = tid + t * 256;
      int m = idx >> 5, kk = idx & 31;    // lanes along k: contiguous 128 B from agg
      int n = row0 + m;
      float v = 0.f;
      if (n < NN) v = agg[(size_t)n * WN + kc + kk];
      As[kk][m] = v;
    }
    #pragma unroll
    for (int t = 0; t < 8; ++t){
      int idx = tid + t * 256;
      int o = idx & 63, kk = idx >> 6;
      Bs[kk][o] = W2[(size_t)(kc + kk) * FOUT + col0 + o];
    }
    __syncthreads();
    #pragma unroll
    for (int kk = 0; kk < 32; ++kk){
      float4 av = *(const float4*)&As[kk][tm * 4];
      float4 bv = *(const float4*)&Bs[kk][tn * 4];
      float a[4] = {av.x, av.y, av.z, av.w};
      float b[4] = {bv.x, bv.y, bv.z, bv.w};
      #pragma unroll
      for (int i = 0; i < 4; ++i)
        #pragma unroll
        for (int j = 0; j < 4; ++j)
          acc[i][j] = fmaf(a[i], b[j], acc[i][j]);
    }
    __syncthreads();
  }
  #pragma unroll
  for (int i = 0; i < 4; ++i){
    int n = row0 + tm * 4 + i;
    if (n < NN){
      float4 sc = *(const float4*)&out[(size_t)n * FOUT + col0 + tn * 4];
      float4 v;
      v.x = silu_f(acc[i][0]) + sc.x;
      v.y = silu_f(acc[i][1]) + sc.y;
      v.z = silu_f(acc[i][2]) + sc.z;
      v.w = silu_f(acc[i][3]) + sc.w;
      *(float4*)&out[(size_t)n * FOUT + col0 + tn * 4] = v;
    }
  }
}

extern "C" void kernel_launch(void* const* d_in, const int* in_sizes, int n_in,
                              void* d_out, int out_size, void* d_ws, size_t ws_size,
                              hipStream_t stream){
  const float* x    = (const float*)d_in[0];
  const float* na   = (const float*)d_in[1];
  const float* eemb = (const float*)d_in[2];
  const float* shp  = (const float*)d_in[3];
  const int*   eidx = (const int*)d_in[4];
  const float* W1   = (const float*)d_in[5];
  const float* Wm1  = (const float*)d_in[6];
  const float* Wm2  = (const float*)d_in[7];
  const float* Wm3  = (const float*)d_in[8];
  const float* W2   = (const float*)d_in[9];
  const float* Wsc  = (const float*)d_in[10];
  float* out  = (float*)d_out;
  float* agg  = (float*)d_ws;                       // [N, 288] f32
  float* hbuf = agg + (size_t)NN * WN;              // [N, 32] f32
  int*   cnt  = (int*)(hbuf + (size_t)NN * CC);     // [N]
  int*   cur  = cnt + NN;                           // [N]
  int*   perm = cur + NN;                           // [E]
  unsigned short* wm2t = (unsigned short*)(perm + EE);   // [64*64] bf16
  unsigned short* wm3t = wm2t + HH * HH;                 // [288*64] bf16
  unsigned short* wscb = wm3t + WN * HH;                 // [256*1024] bf16

  hipMemsetAsync(agg, 0, (size_t)NN * WN * sizeof(float), stream);
  hipMemsetAsync(cnt, 0, (size_t)NN * sizeof(int), stream);
  k_cvt    <<<dim3((WN * HH + 255) / 256), dim3(256), 0, stream>>>(Wm2, Wm3, wm2t, wm3t);
  k_cvtsc  <<<dim3(32, 8), dim3(256), 0, stream>>>(Wsc, wscb);
  k_hist   <<<dim3((EE + 255) / 256), dim3(256),  0, stream>>>(eidx, cnt);
  k_scan   <<<dim3(1),                dim3(1024), 0, stream>>>(cnt, cur);
  k_scatter<<<dim3((EE + 255) / 256), dim3(256),  0, stream>>>(eidx, cur, perm);
  k_h  <<<dim3(NN * CC / 256), dim3(256), 0, stream>>>(x, W1, hbuf);
  k_sc <<<dim3((NN + 63) / 64), dim3(256), 0, stream>>>(x, na, wscb, out);
  k_edge<<<dim3(EE / EPB), dim3(256), 0, stream>>>(eemb, shp, eidx, perm, hbuf, Wm1, wm2t, wm3t, agg);
  k_out<<<dim3((NN + 63) / 64, FOUT / 64), dim3(256), 0, stream>>>(agg, W2, out);
}